// Round 9
// baseline (5490.960 us; speedup 1.0000x reference)
//
#include <hip/hip_runtime.h>
#include <math.h>

#define VSZ 32000
#define EDIM 128
#define HDIM 256
#define BSZ 256
#define SLEN 256
#define ANUM 8
#define SALEN 32
#define G3 768
#define TB 16            // sequences per block (one M-tile)
#define PADW 392         // xh row length in shorts (384 + 8 pad)

// WB: split-bf16 weight fragments: [enc4][kk12][wv8][slot6][hi/lo 2][512 shorts]
// slot = c2*3 + gate (gate 0=r,1=z,2=n). Loads: hi for r,z; hi+lo for n.
#define WB_SHORTS (4 * 12 * 8 * 6 * 2 * 512)    // 2,359,296 shorts = 4.72 MB
#define KK_STRIDE (8 * 6 * 2 * 512)             // 49152 shorts per kk
#define WV_STRIDE (6 * 2 * 512)                 // 6144 shorts per wv
#define OFF_HWT   (WB_SHORTS / 2)               // float offset
#define HWT_SIZE  (1024 * HDIM)
#define OFF_STATE (OFF_HWT + HWT_SIZE)
#define OFF_ACT   (OFF_STATE + BSZ * G3)
#define OFF_EX    (OFF_ACT + 2048 * HDIM)       // u32 region: [48][2 parity][2 hf][2048]
#define EX_U32    (48 * 2 * 2 * 2048)           // 393,216 u32
#define OFF_FLAG  (OFF_EX + EX_U32)             // 96 u32 flags

typedef __attribute__((ext_vector_type(8))) short bf16x8;
typedef __attribute__((ext_vector_type(4))) short bf16x4;
typedef __attribute__((ext_vector_type(4))) float f32x4;

__device__ __forceinline__ unsigned short bf16_rne(float f) {
    unsigned int u = __builtin_bit_cast(unsigned int, f);
    unsigned int r = (u + 0x7FFFu + ((u >> 16) & 1u)) >> 16;
    return (unsigned short)r;
}
__device__ __forceinline__ float bf16_to_f32(unsigned short h) {
    unsigned int u = ((unsigned int)h) << 16;
    return __builtin_bit_cast(float, u);
}

__global__ void prep_frag(const float* __restrict__ Wih, const float* __restrict__ Whh,
                          unsigned short* __restrict__ WB) {
    int idx = blockIdx.x * 256 + threadIdx.x;      // < 1,179,648 (hi elements)
    int q = idx & 7;
    int l = (idx >> 3) & 63;
    int rest = idx >> 9;
    int slot = rest % 6; rest /= 6;                // slot = cc2*3 + g3
    int wv = rest & 7;   rest >>= 3;
    int kk = rest % 12;
    int enc = rest / 12;
    int cc2 = slot / 3, g3 = slot % 3;
    int row = 256 * g3 + 16 * (wv + 8 * cc2) + (l & 15);
    int kloc = 8 * (l >> 4) + q;
    float v;
    if (kk < 4) v = Wih[(enc * G3 + row) * EDIM + 32 * kk + kloc];
    else        v = Whh[(enc * G3 + row) * HDIM + 32 * (kk - 4) + kloc];
    unsigned short hi = bf16_rne(v);
    unsigned short lo = bf16_rne(v - bf16_to_f32(hi));
    size_t base = ((((size_t)(enc * 12 + kk) * 8 + wv) * 6 + slot) * 2) * 512 + l * 8 + q;
    WB[base] = hi;
    WB[base + 512] = lo;
}

__global__ void prep_hwt(const float* __restrict__ hW, float* __restrict__ hWT) {
    int idx = blockIdx.x * 256 + threadIdx.x;
    if (idx >= HWT_SIZE) return;
    int k = idx >> 8;
    int j = idx & 255;
    hWT[idx] = hW[j * 1024 + k];
}

__global__ void init_sync(unsigned int* __restrict__ flags) {
    if (threadIdx.x < 96) flags[threadIdx.x] = 0u;
}

// ---------------- split kernel: 96 long (pairs) + 128 act blocks ----------------
// Long pair (tile, hf): each block owns 128 channels, streams half the weights.
// 16 waves: p = w&7 channel-tile, kh = w>>3.
// Step schedule (pipelined exchange):
//   EARLY : kh0 -> x kks 0..3 ; kh1 -> own-h kks (4+4*hf ..+3)   [no partner dep]
//   MID   : spin partner flag >= t, load partner h(t-1) -> xh    [overlapped w/ early]
//   LATE  : partner-h kks (2 per wave) ; kh1 stages x(t+1), publishes partials
//   GATES : kh0 reduces, computes h(t), stores xh + exbuf; flag=t+1 after barrier
__global__ void __launch_bounds__(1024, 1)
gru_split(const int* __restrict__ obs_t, const int* __restrict__ obs_l,
          const int* __restrict__ look_t, const int* __restrict__ look_l,
          const int* __restrict__ inv_t, const int* __restrict__ inv_l,
          const int* __restrict__ act_t, const int* __restrict__ act_l,
          const float* __restrict__ emb, const float* __restrict__ bih,
          const float* __restrict__ bhh, const unsigned short* __restrict__ WB,
          unsigned int* __restrict__ exbuf, unsigned int* __restrict__ flags,
          float* __restrict__ state, float* __restrict__ act_out) {
    const int bid = blockIdx.x;
    const int x = bid & 7, rr = bid >> 3;   // grid 224 -> rr 0..27
    const int tid = threadIdx.x;
    const int l   = tid & 63;
    const int w   = tid >> 6;     // 0..15
    const int lr  = l & 15;
    const int lg  = l >> 4;

    __shared__ __align__(16) unsigned short xh_hi[TB][PADW];
    __shared__ __align__(16) unsigned short xh_lo[TB][PADW];
    __shared__ __align__(16) float red2[8][3][64][4];   // 24KB partial sums

    if (x < 6 && rr < 16) {
        // ================= LONG encoder, paired-split pipelined path =================
        const int enc  = x >> 1;
        const int tile = (x & 1) * 8 + (rr >> 1);
        const int hf   = rr & 1;
        const int tileG = enc * 16 + tile;     // global long-tile id 0..47
        const int* toks = (enc == 0) ? obs_t : (enc == 1) ? look_t : inv_t;
        const int* lens = (enc == 0) ? obs_l : (enc == 1) ? look_l : inv_l;

        const int p  = w & 7;     // channel-tile within half
        const int kh = w >> 3;    // phase-role half
        const int j  = 16 * p + 128 * hf + lr;   // owned channel (kh==0)

        // init h region to zero (first 512 threads) ; stage x(0) (last 512)
        if (tid < 512) {
            int m = tid >> 5, c = tid & 31;
#pragma unroll
            for (int q = 0; q < 8; ++q) {
                xh_hi[m][EDIM + 8 * c + q] = 0;
                xh_lo[m][EDIM + 8 * c + q] = 0;
            }
        } else {
            int st = tid - 512;
            int m = st >> 5, g = st & 31;
            int tok = toks[(tile * TB + m) * SLEN + 0];
            const float4 v = *(const float4*)(emb + (size_t)tok * EDIM + g * 4);
            float vv[4] = {v.x, v.y, v.z, v.w};
            bf16x4 H, Lo;
#pragma unroll
            for (int q = 0; q < 4; ++q) {
                unsigned short h16 = bf16_rne(vv[q]);
                H[q]  = (short)h16;
                Lo[q] = (short)bf16_rne(vv[q] - bf16_to_f32(h16));
            }
            *(bf16x4*)(&xh_hi[m][g * 4]) = H;
            *(bf16x4*)(&xh_lo[m][g * 4]) = Lo;
        }

        int maxlen = 1;
        for (int s = 0; s < TB; ++s) {
            int L = lens[tile * TB + s];
            if (L < 1) L = 1;
            if (L > maxlen) maxlen = L;
        }
        int lenm[4];
#pragma unroll
        for (int i = 0; i < 4; ++i) {
            int L = lens[tile * TB + 4 * lg + i];
            lenm[i] = (L < 1) ? 1 : L;
        }

        // biases only on kh==0 (added once)
        const float bR  = kh ? 0.f : (bih[enc * G3 + j] + bhh[enc * G3 + j]);
        const float bZ  = kh ? 0.f : (bih[enc * G3 + 256 + j] + bhh[enc * G3 + 256 + j]);
        const float bIN = kh ? 0.f : bih[enc * G3 + 512 + j];
        const float bHN = kh ? 0.f : bhh[enc * G3 + 512 + j];

        float hO[4];
#pragma unroll
        for (int i = 0; i < 4; ++i) hO[i] = 0.f;

        const unsigned short* WBw = WB + (size_t)enc * (12 * KK_STRIDE)
                                       + p * WV_STRIDE + (hf * 3) * 1024 + l * 8;
        unsigned int* fown = flags + tileG * 2 + hf;
        unsigned int* fpar = flags + tileG * 2 + (1 - hf);

        __syncthreads();

        for (int t = 0; t < maxlen; ++t) {
            f32x4 aR  = (f32x4){bR, bR, bR, bR};
            f32x4 aZ  = (f32x4){bZ, bZ, bZ, bZ};
            f32x4 aNX = (f32x4){bIN, bIN, bIN, bIN};
            f32x4 aNH = (f32x4){bHN, bHN, bHN, bHN};

            // ---------- EARLY: no partner dependence ----------
            if (kh == 0) {
                // x kks 0..3 (n -> aNX)
#pragma unroll
                for (int kk = 0; kk < 4; ++kk) {
                    const int off = 32 * kk;
                    bf16x8 Ahi = *(const bf16x8*)(&xh_hi[lr][off + 8 * lg]);
                    bf16x8 Alo = *(const bf16x8*)(&xh_lo[lr][off + 8 * lg]);
                    const unsigned short* wb = WBw + (size_t)kk * KK_STRIDE;
                    bf16x8 BhR = *(const bf16x8*)(wb);
                    bf16x8 BhZ = *(const bf16x8*)(wb + 1024);
                    bf16x8 BhN = *(const bf16x8*)(wb + 2048);
                    bf16x8 BlN = *(const bf16x8*)(wb + 2560);
                    aR  = __builtin_amdgcn_mfma_f32_16x16x32_bf16(Ahi, BhR, aR, 0, 0, 0);
                    aR  = __builtin_amdgcn_mfma_f32_16x16x32_bf16(Alo, BhR, aR, 0, 0, 0);
                    aZ  = __builtin_amdgcn_mfma_f32_16x16x32_bf16(Ahi, BhZ, aZ, 0, 0, 0);
                    aZ  = __builtin_amdgcn_mfma_f32_16x16x32_bf16(Alo, BhZ, aZ, 0, 0, 0);
                    aNX = __builtin_amdgcn_mfma_f32_16x16x32_bf16(Ahi, BhN, aNX, 0, 0, 0);
                    aNX = __builtin_amdgcn_mfma_f32_16x16x32_bf16(Ahi, BlN, aNX, 0, 0, 0);
                    aNX = __builtin_amdgcn_mfma_f32_16x16x32_bf16(Alo, BhN, aNX, 0, 0, 0);
                }
            } else {
                // own-half h kks (n -> aNH)
#pragma unroll
                for (int i2 = 0; i2 < 4; ++i2) {
                    const int kk = 4 + 4 * hf + i2;
                    const int off = EDIM + 32 * (kk - 4);
                    bf16x8 Ahi = *(const bf16x8*)(&xh_hi[lr][off + 8 * lg]);
                    bf16x8 Alo = *(const bf16x8*)(&xh_lo[lr][off + 8 * lg]);
                    const unsigned short* wb = WBw + (size_t)kk * KK_STRIDE;
                    bf16x8 BhR = *(const bf16x8*)(wb);
                    bf16x8 BhZ = *(const bf16x8*)(wb + 1024);
                    bf16x8 BhN = *(const bf16x8*)(wb + 2048);
                    bf16x8 BlN = *(const bf16x8*)(wb + 2560);
                    aR  = __builtin_amdgcn_mfma_f32_16x16x32_bf16(Ahi, BhR, aR, 0, 0, 0);
                    aR  = __builtin_amdgcn_mfma_f32_16x16x32_bf16(Alo, BhR, aR, 0, 0, 0);
                    aZ  = __builtin_amdgcn_mfma_f32_16x16x32_bf16(Ahi, BhZ, aZ, 0, 0, 0);
                    aZ  = __builtin_amdgcn_mfma_f32_16x16x32_bf16(Alo, BhZ, aZ, 0, 0, 0);
                    aNH = __builtin_amdgcn_mfma_f32_16x16x32_bf16(Ahi, BhN, aNH, 0, 0, 0);
                    aNH = __builtin_amdgcn_mfma_f32_16x16x32_bf16(Ahi, BlN, aNH, 0, 0, 0);
                    aNH = __builtin_amdgcn_mfma_f32_16x16x32_bf16(Alo, BhN, aNH, 0, 0, 0);
                }
            }

            // ---------- MID: per-wave spin + load partner h(t-1) ----------
            if (t > 0) {
                if (l == 0) {
                    while (__hip_atomic_load(fpar, __ATOMIC_RELAXED,
                                             __HIP_MEMORY_SCOPE_AGENT) < (unsigned int)t) {
                        __builtin_amdgcn_s_sleep(1);
                    }
                    (void)__hip_atomic_load(fpar, __ATOMIC_ACQUIRE, __HIP_MEMORY_SCOPE_AGENT);
                }
                const unsigned int* exr = exbuf
                    + (((size_t)tileG * 2 + ((t - 1) & 1)) * 2 + (1 - hf)) * 2048;
#pragma unroll
                for (int c = 0; c < 2; ++c) {
                    int idx = w * 128 + l + 64 * c;
                    unsigned int v = __hip_atomic_load(exr + idx, __ATOMIC_RELAXED,
                                                       __HIP_MEMORY_SCOPE_AGENT);
                    int m = idx >> 7, ch = idx & 127;
                    xh_hi[m][EDIM + 128 * (1 - hf) + ch] = (unsigned short)(v >> 16);
                    xh_lo[m][EDIM + 128 * (1 - hf) + ch] = (unsigned short)(v & 0xFFFFu);
                }
            }
            __syncthreads();   // [A] partner h visible; early xh reads done

            const bool more = (t + 1 < maxlen);

            // kh==1: stage x(t+1) (issue global loads before late MFMAs)
            if (kh == 1 && more) {
                int st = tid - 512;
                int m = st >> 5, g = st & 31;
                int tok = toks[(tile * TB + m) * SLEN + (t + 1)];
                const float4 v = *(const float4*)(emb + (size_t)tok * EDIM + g * 4);
                float vv[4] = {v.x, v.y, v.z, v.w};
                bf16x4 H, Lo;
#pragma unroll
                for (int q = 0; q < 4; ++q) {
                    unsigned short h16 = bf16_rne(vv[q]);
                    H[q]  = (short)h16;
                    Lo[q] = (short)bf16_rne(vv[q] - bf16_to_f32(h16));
                }
                *(bf16x4*)(&xh_hi[m][g * 4]) = H;
                *(bf16x4*)(&xh_lo[m][g * 4]) = Lo;
            }

            // ---------- LATE: partner-half h kks (2 per wave, n -> aNH) ----------
            {
                const int kk0 = 4 + 4 * (1 - hf) + 2 * kh;
#pragma unroll
                for (int i2 = 0; i2 < 2; ++i2) {
                    const int kk = kk0 + i2;
                    const int off = EDIM + 32 * (kk - 4);
                    bf16x8 Ahi = *(const bf16x8*)(&xh_hi[lr][off + 8 * lg]);
                    bf16x8 Alo = *(const bf16x8*)(&xh_lo[lr][off + 8 * lg]);
                    const unsigned short* wb = WBw + (size_t)kk * KK_STRIDE;
                    bf16x8 BhR = *(const bf16x8*)(wb);
                    bf16x8 BhZ = *(const bf16x8*)(wb + 1024);
                    bf16x8 BhN = *(const bf16x8*)(wb + 2048);
                    bf16x8 BlN = *(const bf16x8*)(wb + 2560);
                    aR  = __builtin_amdgcn_mfma_f32_16x16x32_bf16(Ahi, BhR, aR, 0, 0, 0);
                    aR  = __builtin_amdgcn_mfma_f32_16x16x32_bf16(Alo, BhR, aR, 0, 0, 0);
                    aZ  = __builtin_amdgcn_mfma_f32_16x16x32_bf16(Ahi, BhZ, aZ, 0, 0, 0);
                    aZ  = __builtin_amdgcn_mfma_f32_16x16x32_bf16(Alo, BhZ, aZ, 0, 0, 0);
                    aNH = __builtin_amdgcn_mfma_f32_16x16x32_bf16(Ahi, BhN, aNH, 0, 0, 0);
                    aNH = __builtin_amdgcn_mfma_f32_16x16x32_bf16(Ahi, BlN, aNH, 0, 0, 0);
                    aNH = __builtin_amdgcn_mfma_f32_16x16x32_bf16(Alo, BhN, aNH, 0, 0, 0);
                }
            }

            if (kh == 1) {
                *(f32x4*)(&red2[p][0][l][0]) = aR;
                *(f32x4*)(&red2[p][1][l][0]) = aZ;
                *(f32x4*)(&red2[p][2][l][0]) = aNH;
            }
            __syncthreads();   // [B] partials ready

            if (kh == 0) {
                f32x4 rRp = *(const f32x4*)(&red2[p][0][l][0]);
                f32x4 rZp = *(const f32x4*)(&red2[p][1][l][0]);
                f32x4 rNp = *(const f32x4*)(&red2[p][2][l][0]);
                aR += rRp; aZ += rZp; aNH += rNp;
                unsigned int* exw = exbuf + (((size_t)tileG * 2 + (t & 1)) * 2 + hf) * 2048;
#pragma unroll
                for (int i = 0; i < 4; ++i) {
                    int m = 4 * lg + i;
                    float r = 1.f / (1.f + expf(-aR[i]));
                    float z = 1.f / (1.f + expf(-aZ[i]));
                    float n = tanhf(aNX[i] + r * aNH[i]);
                    float hv = (1.f - z) * n + z * hO[i];
                    hv = (t < lenm[i]) ? hv : hO[i];
                    hO[i] = hv;
                    unsigned short h16 = bf16_rne(hv);
                    unsigned short l16 = bf16_rne(hv - bf16_to_f32(h16));
                    xh_hi[m][EDIM + j] = h16;
                    xh_lo[m][EDIM + j] = l16;
                    if (more) {
                        unsigned int pk = ((unsigned int)h16 << 16) | (unsigned int)l16;
                        __hip_atomic_store(exw + m * 128 + 16 * p + lr, pk,
                                           __ATOMIC_RELAXED, __HIP_MEMORY_SCOPE_AGENT);
                    }
                }
            }
            __syncthreads();   // [C] h(t) in LDS; exbuf stores drained (vmcnt@barrier)
            if (more && tid == 0) {
                __hip_atomic_store(fown, (unsigned int)(t + 1),
                                   __ATOMIC_RELEASE, __HIP_MEMORY_SCOPE_AGENT);
            }
            // next iteration's EARLY starts immediately; flag store proceeds async
        }

        // outputs: kh==0 waves own (m = 4*lg+i, channel j)
        if (kh == 0) {
#pragma unroll
            for (int i = 0; i < 4; ++i) {
                int sg = tile * TB + 4 * lg + i;
                state[sg * G3 + enc * HDIM + j] = hO[i];
            }
        }
    } else {
        // ================= ACT encoder, solo path =================
        const int enc = 3;
        int tile;
        if (x >= 6) tile = rr * 2 + (x - 6);
        else        tile = 56 + (rr - 16) * 6 + x;
        const int* toks = act_t;
        const int* lens = act_l;
        const int S = SALEN;

        const int wvb = w & 7;
        const int c2  = w >> 3;
        const int j   = 16 * wvb + 128 * c2 + lr;

        if (tid < 512) {
            int m = tid >> 5, c = tid & 31;
#pragma unroll
            for (int q = 0; q < 8; ++q) {
                xh_hi[m][EDIM + 8 * c + q] = 0;
                xh_lo[m][EDIM + 8 * c + q] = 0;
            }
        }

        int maxlen = 1;
        for (int s = 0; s < TB; ++s) {
            int L = lens[tile * TB + s];
            if (L < 1) L = 1;
            if (L > maxlen) maxlen = L;
        }
        int lenm[4];
#pragma unroll
        for (int i = 0; i < 4; ++i) {
            int L = lens[tile * TB + 4 * lg + i];
            lenm[i] = (L < 1) ? 1 : L;
        }

        const float bR  = bih[enc * G3 + j] + bhh[enc * G3 + j];
        const float bZ  = bih[enc * G3 + 256 + j] + bhh[enc * G3 + 256 + j];
        const float bIN = bih[enc * G3 + 512 + j];
        const float bHN = bhh[enc * G3 + 512 + j];

        float hO[4];
#pragma unroll
        for (int i = 0; i < 4; ++i) hO[i] = 0.f;

        auto stage = [&](int tt) {
            if (tid < 512) {
                int m = tid >> 5, g = tid & 31;
                int tok = toks[(tile * TB + m) * S + tt];
                const float4 v = *(const float4*)(emb + (size_t)tok * EDIM + g * 4);
                float vv[4] = {v.x, v.y, v.z, v.w};
                bf16x4 H, Lo;
#pragma unroll
                for (int q = 0; q < 4; ++q) {
                    unsigned short h16 = bf16_rne(vv[q]);
                    H[q]  = (short)h16;
                    Lo[q] = (short)bf16_rne(vv[q] - bf16_to_f32(h16));
                }
                *(bf16x4*)(&xh_hi[m][g * 4]) = H;
                *(bf16x4*)(&xh_lo[m][g * 4]) = Lo;
            }
        };

        const unsigned short* WBw = WB + (size_t)enc * (12 * KK_STRIDE)
                                       + wvb * WV_STRIDE + (c2 * 3) * 1024 + l * 8;

        stage(0);
        __syncthreads();

        for (int t = 0; t < maxlen; ++t) {
            f32x4 aR  = (f32x4){bR, bR, bR, bR};
            f32x4 aZ  = (f32x4){bZ, bZ, bZ, bZ};
            f32x4 aNX = (f32x4){bIN, bIN, bIN, bIN};
            f32x4 aNH = (f32x4){bHN, bHN, bHN, bHN};

#pragma unroll 2
            for (int kk = 0; kk < 12; ++kk) {
                const int off = (kk < 4) ? 32 * kk : EDIM + 32 * (kk - 4);
                bf16x8 Ahi = *(const bf16x8*)(&xh_hi[lr][off + 8 * lg]);
                bf16x8 Alo = *(const bf16x8*)(&xh_lo[lr][off + 8 * lg]);
                const unsigned short* wb = WBw + (size_t)kk * KK_STRIDE;
                bf16x8 BhR = *(const bf16x8*)(wb);
                bf16x8 BhZ = *(const bf16x8*)(wb + 1024);
                bf16x8 BhN = *(const bf16x8*)(wb + 2048);
                bf16x8 BlN = *(const bf16x8*)(wb + 2560);
                aR = __builtin_amdgcn_mfma_f32_16x16x32_bf16(Ahi, BhR, aR, 0, 0, 0);
                aR = __builtin_amdgcn_mfma_f32_16x16x32_bf16(Alo, BhR, aR, 0, 0, 0);
                aZ = __builtin_amdgcn_mfma_f32_16x16x32_bf16(Ahi, BhZ, aZ, 0, 0, 0);
                aZ = __builtin_amdgcn_mfma_f32_16x16x32_bf16(Alo, BhZ, aZ, 0, 0, 0);
                if (kk < 4) {
                    aNX = __builtin_amdgcn_mfma_f32_16x16x32_bf16(Ahi, BhN, aNX, 0, 0, 0);
                    aNX = __builtin_amdgcn_mfma_f32_16x16x32_bf16(Ahi, BlN, aNX, 0, 0, 0);
                    aNX = __builtin_amdgcn_mfma_f32_16x16x32_bf16(Alo, BhN, aNX, 0, 0, 0);
                } else {
                    aNH = __builtin_amdgcn_mfma_f32_16x16x32_bf16(Ahi, BhN, aNH, 0, 0, 0);
                    aNH = __builtin_amdgcn_mfma_f32_16x16x32_bf16(Ahi, BlN, aNH, 0, 0, 0);
                    aNH = __builtin_amdgcn_mfma_f32_16x16x32_bf16(Alo, BhN, aNH, 0, 0, 0);
                }
            }

            __syncthreads();

#pragma unroll
            for (int i = 0; i < 4; ++i) {
                int m = 4 * lg + i;
                float r = 1.f / (1.f + expf(-aR[i]));
                float z = 1.f / (1.f + expf(-aZ[i]));
                float n = tanhf(aNX[i] + r * aNH[i]);
                float hv = (1.f - z) * n + z * hO[i];
                hv = (t < lenm[i]) ? hv : hO[i];
                hO[i] = hv;
                unsigned short h16 = bf16_rne(hv);
                xh_hi[m][EDIM + j] = h16;
                xh_lo[m][EDIM + j] = bf16_rne(hv - bf16_to_f32(h16));
            }
            if (t + 1 < maxlen) stage(t + 1);
            __syncthreads();
        }

#pragma unroll
        for (int i = 0; i < 4; ++i) {
            int sg = tile * TB + 4 * lg + i;
            act_out[sg * HDIM + j] = hO[i];
        }
    }
}

__global__ void __launch_bounds__(256)
mlp_kernel(const float* __restrict__ state, const float* __restrict__ act_out,
           const float* __restrict__ hWT, const float* __restrict__ hb,
           const float* __restrict__ sW, const float* __restrict__ sb,
           float* __restrict__ q) {
    int b = blockIdx.x;
    int j = threadIdx.x;
    __shared__ float st[G3];
    __shared__ float ab[ANUM][HDIM];
#pragma unroll
    for (int i = 0; i < 3; ++i) st[i * 256 + j] = state[b * G3 + i * 256 + j];
#pragma unroll
    for (int i = 0; i < ANUM; ++i) ab[i][j] = act_out[(b * ANUM + i) * HDIM + j];
    __syncthreads();

    float accS = 0.f;
#pragma unroll 4
    for (int k = 0; k < G3; ++k) accS += st[k] * hWT[k * HDIM + j];

    float accA[ANUM];
#pragma unroll
    for (int i = 0; i < ANUM; ++i) accA[i] = 0.f;
    for (int k = 0; k < HDIM; ++k) {
        float w = hWT[(G3 + k) * HDIM + j];
#pragma unroll
        for (int i = 0; i < ANUM; ++i) accA[i] += ab[i][k] * w;
    }

    float base = hb[j] + accS;
    float p[ANUM];
#pragma unroll
    for (int i = 0; i < ANUM; ++i) {
        float zz = base + accA[i];
        zz = zz > 0.f ? zz : 0.f;
        p[i] = zz * sW[j];
    }

    __shared__ float wsum[ANUM][4];
#pragma unroll
    for (int i = 0; i < ANUM; ++i) {
        float v = p[i];
        for (int off = 32; off >= 1; off >>= 1) v += __shfl_down(v, off, 64);
        if ((j & 63) == 0) wsum[i][j >> 6] = v;
    }
    __syncthreads();
    if (j < ANUM) q[b * ANUM + j] = wsum[j][0] + wsum[j][1] + wsum[j][2] + wsum[j][3] + sb[0];
}

extern "C" void kernel_launch(void* const* d_in, const int* in_sizes, int n_in,
                              void* d_out, int out_size, void* d_ws, size_t ws_size,
                              hipStream_t stream) {
    const int* obs_t  = (const int*)d_in[0];
    const int* obs_l  = (const int*)d_in[1];
    const int* look_t = (const int*)d_in[2];
    const int* look_l = (const int*)d_in[3];
    const int* inv_t  = (const int*)d_in[4];
    const int* inv_l  = (const int*)d_in[5];
    const int* act_t  = (const int*)d_in[6];
    const int* act_l  = (const int*)d_in[7];
    const float* emb  = (const float*)d_in[8];
    const float* Wih  = (const float*)d_in[9];
    const float* Whh  = (const float*)d_in[10];
    const float* bih  = (const float*)d_in[11];
    const float* bhh  = (const float*)d_in[12];
    const float* hW   = (const float*)d_in[13];
    const float* hb   = (const float*)d_in[14];
    const float* sW   = (const float*)d_in[15];
    const float* sb   = (const float*)d_in[16];

    float* ws    = (float*)d_ws;
    unsigned short* WB = (unsigned short*)d_ws;
    float* hWT   = ws + OFF_HWT;
    float* state = ws + OFF_STATE;
    float* act_o = ws + OFF_ACT;
    unsigned int* exbuf = (unsigned int*)(ws + OFF_EX);
    unsigned int* flags = (unsigned int*)(ws + OFF_FLAG);

    prep_frag<<<(WB_SHORTS / 2 + 255) / 256, 256, 0, stream>>>(Wih, Whh, WB);
    prep_hwt<<<(HWT_SIZE + 255) / 256, 256, 0, stream>>>(hW, hWT);
    init_sync<<<1, 128, 0, stream>>>(flags);
    gru_split<<<224, 1024, 0, stream>>>(obs_t, obs_l, look_t, look_l, inv_t, inv_l,
                                        act_t, act_l, emb, bih, bhh, WB,
                                        exbuf, flags, state, act_o);
    mlp_kernel<<<256, 256, 0, stream>>>(state, act_o, hWT, hb, sW, sb, (float*)d_out);
}

// Round 10
// 1636.224 us; speedup vs baseline: 3.3559x; 3.3559x over previous
//
#include <hip/hip_runtime.h>
#include <math.h>

#define VSZ 32000
#define EDIM 128
#define HDIM 256
#define BSZ 256
#define SLEN 256
#define ANUM 8
#define SALEN 32
#define G3 768
#define TB 16            // sequences per block (one M-tile)
#define PADW 392         // xh row length in shorts (384 + 8 pad)

// WB: split-bf16 weight fragments: [enc4][kk12][wv8][slot6][hi/lo 2][512 shorts]
// slot = c2*3 + gate (gate 0=r,1=z,2=n). Recurrence loads hi-only for ALL gates
// (A-side keeps hi+lo); lo fragments remain in WB but are never fetched.
#define WB_SHORTS (4 * 12 * 8 * 6 * 2 * 512)    // 2,359,296 shorts = 4.72 MB
#define KK_STRIDE (8 * 6 * 2 * 512)             // 49152 shorts per kk
#define WV_STRIDE (6 * 2 * 512)                 // 6144 shorts per wv
#define OFF_HWT   (WB_SHORTS / 2)               // float offset
#define HWT_SIZE  (1024 * HDIM)
#define OFF_STATE (OFF_HWT + HWT_SIZE)
#define OFF_ACT   (OFF_STATE + BSZ * G3)

typedef __attribute__((ext_vector_type(8))) short bf16x8;
typedef __attribute__((ext_vector_type(4))) short bf16x4;
typedef __attribute__((ext_vector_type(4))) float f32x4;

__device__ __forceinline__ unsigned short bf16_rne(float f) {
    unsigned int u = __builtin_bit_cast(unsigned int, f);
    unsigned int r = (u + 0x7FFFu + ((u >> 16) & 1u)) >> 16;
    return (unsigned short)r;
}
__device__ __forceinline__ float bf16_to_f32(unsigned short h) {
    unsigned int u = ((unsigned int)h) << 16;
    return __builtin_bit_cast(float, u);
}

// B-fragment: lane l elem q -> B[k = 32*kk + 8*(l>>4) + q][n], n = 256*g3 + 16*(wv+8*cc2) + (l&15)
__global__ void prep_frag(const float* __restrict__ Wih, const float* __restrict__ Whh,
                          unsigned short* __restrict__ WB) {
    int idx = blockIdx.x * 256 + threadIdx.x;      // < 1,179,648 (hi elements)
    int q = idx & 7;
    int l = (idx >> 3) & 63;
    int rest = idx >> 9;
    int slot = rest % 6; rest /= 6;                // slot = cc2*3 + g3
    int wv = rest & 7;   rest >>= 3;
    int kk = rest % 12;
    int enc = rest / 12;
    int cc2 = slot / 3, g3 = slot % 3;
    int row = 256 * g3 + 16 * (wv + 8 * cc2) + (l & 15);
    int kloc = 8 * (l >> 4) + q;
    float v;
    if (kk < 4) v = Wih[(enc * G3 + row) * EDIM + 32 * kk + kloc];
    else        v = Whh[(enc * G3 + row) * HDIM + 32 * (kk - 4) + kloc];
    unsigned short hi = bf16_rne(v);
    unsigned short lo = bf16_rne(v - bf16_to_f32(hi));
    size_t base = ((((size_t)(enc * 12 + kk) * 8 + wv) * 6 + slot) * 2) * 512 + l * 8 + q;
    WB[base] = hi;
    WB[base + 512] = lo;
}

__global__ void prep_hwt(const float* __restrict__ hW, float* __restrict__ hWT) {
    int idx = blockIdx.x * 256 + threadIdx.x;
    if (idx >= HWT_SIZE) return;
    int k = idx >> 8;
    int j = idx & 255;
    hWT[idx] = hW[j * 1024 + k];
}

// 1024 threads = 16 waves. Wave w owns ONE channel-tile: channels
// j = 16*(w&7) + 128*(w>>3) + lr. 4 waves/SIMD.
// All gate weights pure bf16 (hi); A-side (x,h) split hi+lo.
__global__ void __launch_bounds__(1024, 1)
gru_mfma(const int* __restrict__ obs_t, const int* __restrict__ obs_l,
         const int* __restrict__ look_t, const int* __restrict__ look_l,
         const int* __restrict__ inv_t, const int* __restrict__ inv_l,
         const int* __restrict__ act_t, const int* __restrict__ act_l,
         const float* __restrict__ emb, const float* __restrict__ bih,
         const float* __restrict__ bhh, const unsigned short* __restrict__ WB,
         float* __restrict__ state, float* __restrict__ act_out) {
    const int bid = blockIdx.x;
    // XCD-aware mapping: bid%8 ~ XCD. XCD pair {0,1}->enc0, {2,3}->enc1,
    // {4,5}->enc2; act fills XCDs 6,7 plus the leftover slots everywhere.
    const int x = bid & 7, rr = bid >> 3;   // grid = 176 -> rr in 0..21
    int enc, tile, S;
    const int* toks;
    const int* lens;
    if (x < 6 && rr < 8) {
        enc = x >> 1; tile = (x & 1) * 8 + rr; S = SLEN;
        toks = (enc == 0) ? obs_t : (enc == 1) ? look_t : inv_t;
        lens = (enc == 0) ? obs_l : (enc == 1) ? look_l : inv_l;
    } else {
        enc = 3; S = SALEN;
        tile = (x >= 6) ? (rr * 2 + (x - 6)) : (44 + (rr - 8) * 6 + x);
        toks = act_t; lens = act_l;
    }
    const int tid = threadIdx.x;
    const int l   = tid & 63;
    const int w   = tid >> 6;     // 0..15
    const int wvb = w & 7;        // WB wv index
    const int c2  = w >> 3;       // slot group
    const int lr  = l & 15;
    const int lg  = l >> 4;
    const int j   = 16 * wvb + 128 * c2 + lr;   // owned channel

    __shared__ __align__(16) unsigned short xh_hi[TB][PADW];
    __shared__ __align__(16) unsigned short xh_lo[TB][PADW];

    // init h region [128,384) to zero (first 512 threads)
    if (tid < 512) {
        int m = tid >> 5, c = tid & 31;
#pragma unroll
        for (int q = 0; q < 8; ++q) {
            xh_hi[m][EDIM + 8 * c + q] = 0;
            xh_lo[m][EDIM + 8 * c + q] = 0;
        }
    }

    int maxlen = 1;
    for (int s = 0; s < TB; ++s) {
        int L = lens[tile * TB + s];
        if (L < 1) L = 1;
        if (L > maxlen) maxlen = L;
    }
    int lenm[4];
#pragma unroll
    for (int i = 0; i < 4; ++i) {
        int L = lens[tile * TB + 4 * lg + i];
        lenm[i] = (L < 1) ? 1 : L;
    }

    const float bR  = bih[enc * G3 + j] + bhh[enc * G3 + j];
    const float bZ  = bih[enc * G3 + 256 + j] + bhh[enc * G3 + 256 + j];
    const float bIN = bih[enc * G3 + 512 + j];
    const float bHN = bhh[enc * G3 + 512 + j];

    float hO[4];
#pragma unroll
    for (int i = 0; i < 4; ++i) hO[i] = 0.f;

    // stage x_t: first 512 threads, each 4 floats of one seq row
    auto stage = [&](int tt) {
        if (tid < 512) {
            int m = tid >> 5, g = tid & 31;
            int tok = toks[(tile * TB + m) * S + tt];
            const float4 v = *(const float4*)(emb + (size_t)tok * EDIM + g * 4);
            float vv[4] = {v.x, v.y, v.z, v.w};
            bf16x4 H, Lo;
#pragma unroll
            for (int q = 0; q < 4; ++q) {
                unsigned short h16 = bf16_rne(vv[q]);
                H[q]  = (short)h16;
                Lo[q] = (short)bf16_rne(vv[q] - bf16_to_f32(h16));
            }
            *(bf16x4*)(&xh_hi[m][g * 4]) = H;
            *(bf16x4*)(&xh_lo[m][g * 4]) = Lo;
        }
    };

    // this wave's fragment base: its wv slice, its c2 slot group
    const unsigned short* WBw = WB + (size_t)enc * (12 * KK_STRIDE)
                                   + wvb * WV_STRIDE + (c2 * 3) * 1024 + l * 8;

    stage(0);
    __syncthreads();

    for (int t = 0; t < maxlen; ++t) {
        f32x4 aR  = (f32x4){bR, bR, bR, bR};
        f32x4 aZ  = (f32x4){bZ, bZ, bZ, bZ};
        f32x4 aNX = (f32x4){bIN, bIN, bIN, bIN};
        f32x4 aNH = (f32x4){bHN, bHN, bHN, bHN};

#pragma unroll 2
        for (int kk = 0; kk < 12; ++kk) {
            const int off = (kk < 4) ? 32 * kk : EDIM + 32 * (kk - 4);
            bf16x8 Ahi = *(const bf16x8*)(&xh_hi[lr][off + 8 * lg]);
            bf16x8 Alo = *(const bf16x8*)(&xh_lo[lr][off + 8 * lg]);
            const unsigned short* wb = WBw + (size_t)kk * KK_STRIDE;
            bf16x8 BhR = *(const bf16x8*)(wb);            // r: hi only
            bf16x8 BhZ = *(const bf16x8*)(wb + 1024);     // z: hi only
            bf16x8 BhN = *(const bf16x8*)(wb + 2048);     // n: hi only
            aR = __builtin_amdgcn_mfma_f32_16x16x32_bf16(Ahi, BhR, aR, 0, 0, 0);
            aR = __builtin_amdgcn_mfma_f32_16x16x32_bf16(Alo, BhR, aR, 0, 0, 0);
            aZ = __builtin_amdgcn_mfma_f32_16x16x32_bf16(Ahi, BhZ, aZ, 0, 0, 0);
            aZ = __builtin_amdgcn_mfma_f32_16x16x32_bf16(Alo, BhZ, aZ, 0, 0, 0);
            if (kk < 4) {
                aNX = __builtin_amdgcn_mfma_f32_16x16x32_bf16(Ahi, BhN, aNX, 0, 0, 0);
                aNX = __builtin_amdgcn_mfma_f32_16x16x32_bf16(Alo, BhN, aNX, 0, 0, 0);
            } else {
                aNH = __builtin_amdgcn_mfma_f32_16x16x32_bf16(Ahi, BhN, aNH, 0, 0, 0);
                aNH = __builtin_amdgcn_mfma_f32_16x16x32_bf16(Alo, BhN, aNH, 0, 0, 0);
            }
        }

        __syncthreads();   // all xh reads of this step done

        // gates + h update; C layout: row m = 4*lg + i, col = lr
#pragma unroll
        for (int i = 0; i < 4; ++i) {
            int m = 4 * lg + i;
            float r = 1.f / (1.f + expf(-aR[i]));
            float z = 1.f / (1.f + expf(-aZ[i]));
            float n = tanhf(aNX[i] + r * aNH[i]);
            float hv = (1.f - z) * n + z * hO[i];
            hv = (t < lenm[i]) ? hv : hO[i];
            hO[i] = hv;
            unsigned short h16 = bf16_rne(hv);
            xh_hi[m][EDIM + j] = h16;
            xh_lo[m][EDIM + j] = bf16_rne(hv - bf16_to_f32(h16));
        }
        if (t + 1 < maxlen) stage(t + 1);
        __syncthreads();
    }

    // outputs: lane owns (m = 4*lg+i, channel j)
#pragma unroll
    for (int i = 0; i < 4; ++i) {
        int sg = tile * TB + 4 * lg + i;
        if (enc < 3) state[sg * G3 + enc * HDIM + j] = hO[i];
        else         act_out[sg * HDIM + j] = hO[i];
    }
}

__global__ void __launch_bounds__(256)
mlp_kernel(const float* __restrict__ state, const float* __restrict__ act_out,
           const float* __restrict__ hWT, const float* __restrict__ hb,
           const float* __restrict__ sW, const float* __restrict__ sb,
           float* __restrict__ q) {
    int b = blockIdx.x;
    int j = threadIdx.x;
    __shared__ float st[G3];
    __shared__ float ab[ANUM][HDIM];
#pragma unroll
    for (int i = 0; i < 3; ++i) st[i * 256 + j] = state[b * G3 + i * 256 + j];
#pragma unroll
    for (int i = 0; i < ANUM; ++i) ab[i][j] = act_out[(b * ANUM + i) * HDIM + j];
    __syncthreads();

    float accS = 0.f;
#pragma unroll 4
    for (int k = 0; k < G3; ++k) accS += st[k] * hWT[k * HDIM + j];

    float accA[ANUM];
#pragma unroll
    for (int i = 0; i < ANUM; ++i) accA[i] = 0.f;
    for (int k = 0; k < HDIM; ++k) {
        float w = hWT[(G3 + k) * HDIM + j];
#pragma unroll
        for (int i = 0; i < ANUM; ++i) accA[i] += ab[i][k] * w;
    }

    float base = hb[j] + accS;
    float p[ANUM];
#pragma unroll
    for (int i = 0; i < ANUM; ++i) {
        float zz = base + accA[i];
        zz = zz > 0.f ? zz : 0.f;
        p[i] = zz * sW[j];
    }

    __shared__ float wsum[ANUM][4];
#pragma unroll
    for (int i = 0; i < ANUM; ++i) {
        float v = p[i];
        for (int off = 32; off >= 1; off >>= 1) v += __shfl_down(v, off, 64);
        if ((j & 63) == 0) wsum[i][j >> 6] = v;
    }
    __syncthreads();
    if (j < ANUM) q[b * ANUM + j] = wsum[j][0] + wsum[j][1] + wsum[j][2] + wsum[j][3] + sb[0];
}

extern "C" void kernel_launch(void* const* d_in, const int* in_sizes, int n_in,
                              void* d_out, int out_size, void* d_ws, size_t ws_size,
                              hipStream_t stream) {
    const int* obs_t  = (const int*)d_in[0];
    const int* obs_l  = (const int*)d_in[1];
    const int* look_t = (const int*)d_in[2];
    const int* look_l = (const int*)d_in[3];
    const int* inv_t  = (const int*)d_in[4];
    const int* inv_l  = (const int*)d_in[5];
    const int* act_t  = (const int*)d_in[6];
    const int* act_l  = (const int*)d_in[7];
    const float* emb  = (const float*)d_in[8];
    const float* Wih  = (const float*)d_in[9];
    const float* Whh  = (const float*)d_in[10];
    const float* bih  = (const float*)d_in[11];
    const float* bhh  = (const float*)d_in[12];
    const float* hW   = (const float*)d_in[13];
    const float* hb   = (const float*)d_in[14];
    const float* sW   = (const float*)d_in[15];
    const float* sb   = (const float*)d_in[16];

    float* ws    = (float*)d_ws;
    unsigned short* WB = (unsigned short*)d_ws;
    float* hWT   = ws + OFF_HWT;
    float* state = ws + OFF_STATE;
    float* act_o = ws + OFF_ACT;

    prep_frag<<<(WB_SHORTS / 2 + 255) / 256, 256, 0, stream>>>(Wih, Whh, WB);
    prep_hwt<<<(HWT_SIZE + 255) / 256, 256, 0, stream>>>(hW, hWT);
    gru_mfma<<<176, 1024, 0, stream>>>(obs_t, obs_l, look_t, look_l, inv_t, inv_l,
                                       act_t, act_l, emb, bih, bhh, WB,
                                       state, act_o);
    mlp_kernel<<<256, 256, 0, stream>>>(state, act_o, hWT, hb, sW, sb, (float*)d_out);
}